// Round 7
// baseline (61.665 us; speedup 1.0000x reference)
//
#include <hip/hip_runtime.h>

#define L_SEQ 2048
#define HEADS 16
#define DIM   64
#define TILE  16          // rows per WAVE; 4 independent waves per 256-thread block

typedef __attribute__((ext_vector_type(8))) short bf16x8;
typedef __attribute__((ext_vector_type(4))) float f32x4;

static __device__ __forceinline__ unsigned short f2bf_rtne(float f) {
    unsigned int u = __builtin_bit_cast(unsigned int, f);
    u += 0x7fffu + ((u >> 16) & 1u);
    return (unsigned short)(u >> 16);
}
// pack hi16(a) | hi16(b)<<16 in ONE v_perm_b32 (truncation rounding — score
// path error budget is ~1000x the threshold sensitivity)
static __device__ __forceinline__ unsigned int pk2(float a, float b) {
    return __builtin_amdgcn_perm(__builtin_bit_cast(unsigned int, b),
                                 __builtin_bit_cast(unsigned int, a), 0x07060302u);
}

__global__ void prep_w_kernel(const float* __restrict__ W, unsigned short* __restrict__ wbf) {
    int i = blockIdx.x * 256 + threadIdx.x;
    if (i < DIM * DIM) wbf[i] = f2bf_rtne(W[i]);
}

static __device__ __forceinline__ bf16x8 load_bfrag(const unsigned short* wbf,
                                                    const float* W, int n, int k0) {
    if (wbf) return *(const bf16x8*)(wbf + n * 64 + k0);
    const float* wr = W + n * 64 + k0;
    float4 w0 = *(const float4*)wr;
    float4 w1 = *(const float4*)(wr + 4);
    uint4 p;
    p.x = pk2(w0.x, w0.y); p.y = pk2(w0.z, w0.w);
    p.z = pk2(w1.x, w1.y); p.w = pk2(w1.z, w1.w);
    return __builtin_bit_cast(bf16x8, p);
}

// Fully wave-independent: one wave = (b, h, 16 consecutive l).
// ZERO LDS, ZERO __syncthreads (R3-R5 post-mortems: barrier-convoy-bound).
// All data flows through registers + a few cross-lane shuffles.
__global__ __launch_bounds__(256, 6) void betweenness_rope_kernel(
    const float* __restrict__ x, const float* __restrict__ W,
    const unsigned short* __restrict__ wbf, const float* __restrict__ gate,
    float* __restrict__ out)
{
    const int tid  = threadIdx.x;
    const int lane = tid & 63;
    const int wv   = tid >> 6;
    const int la   = lane & 15, lg = lane >> 4;
    const int l0   = (blockIdx.x * 4 + wv) * TILE;
    const int h    = blockIdx.y;
    const int b    = blockIdx.z;
    const int bh_off = (b * L_SEQ * HEADS + h) * DIM;

    // ---- P1: delta rows straight into MFMA A-fragment layout ----
    // delta row r = x[l0+r] - x[l0-1+r]; lane (la,lg): row r=la (mt=0) or r=16
    // (mt=1, all lanes clamped -> duplicated row feeds only unused D rows).
    bf16x8 afrag[2][2];
    #pragma unroll
    for (int mt = 0; mt < 2; ++mt) {
        int r  = mt ? 16 : la;
        int g0 = max(l0 - 1 + r, 0);
        int g1 = min(l0 + r, L_SEQ - 1);
        const float* p0 = x + bh_off + g0 * (HEADS * DIM) + lg * 8;
        const float* p1 = x + bh_off + g1 * (HEADS * DIM) + lg * 8;
        #pragma unroll
        for (int kh = 0; kh < 2; ++kh) {
            float4 a0 = *(const float4*)(p0 + kh * 32);
            float4 a1 = *(const float4*)(p0 + kh * 32 + 4);
            float4 b0 = *(const float4*)(p1 + kh * 32);
            float4 b1 = *(const float4*)(p1 + kh * 32 + 4);
            uint4 o;
            o.x = pk2(b0.x - a0.x, b0.y - a0.y);
            o.y = pk2(b0.z - a0.z, b0.w - a0.w);
            o.z = pk2(b1.x - a1.x, b1.y - a1.y);
            o.w = pk2(b1.z - a1.z, b1.w - a1.w);
            afrag[mt][kh] = __builtin_bit_cast(bf16x8, o);
        }
    }

    // ---- P2: E = Delta @ W^T (MFMA) + in-register Gram band ----
    // D layout: lane holds E[lg*4+q][16nt+la] in e0[q]; E[16][16nt+la] in e1[0].
    float sq[4] = {0.f, 0.f, 0.f, 0.f};   // -> n1[lg*4+q] after la-reduction
    float pr[4] = {0.f, 0.f, 0.f, 0.f};   // -> g1[lg*4+q]
    float sq16  = 0.f;                    // -> n1[16]
    #pragma unroll
    for (int nt = 0; nt < 4; ++nt) {
        bf16x8 b0 = load_bfrag(wbf, W, 16 * nt + la, lg * 8);
        bf16x8 b1 = load_bfrag(wbf, W, 16 * nt + la, lg * 8 + 32);
        f32x4 e0 = {0.f, 0.f, 0.f, 0.f};
        f32x4 e1 = {0.f, 0.f, 0.f, 0.f};
        e0 = __builtin_amdgcn_mfma_f32_16x16x32_bf16(afrag[0][0], b0, e0, 0, 0, 0);
        e0 = __builtin_amdgcn_mfma_f32_16x16x32_bf16(afrag[0][1], b1, e0, 0, 0, 0);
        e1 = __builtin_amdgcn_mfma_f32_16x16x32_bf16(afrag[1][0], b0, e1, 0, 0, 0);
        e1 = __builtin_amdgcn_mfma_f32_16x16x32_bf16(afrag[1][1], b1, e1, 0, 0, 0);
        #pragma unroll
        for (int q = 0; q < 4; ++q) sq[q] = fmaf(e0[q], e0[q], sq[q]);
        sq16  = fmaf(e1[0], e1[0], sq16);
        pr[0] = fmaf(e0[0], e0[1], pr[0]);
        pr[1] = fmaf(e0[1], e0[2], pr[1]);
        pr[2] = fmaf(e0[2], e0[3], pr[2]);
        // row lg*4+4: next lg's e0[0]; for lg==3 it's row 16 = own e1[0] (clamped dup)
        float up0  = __shfl(e0[0], (lane + 16) & 63);
        float part = (lg == 3) ? e1[0] : up0;
        pr[3] = fmaf(e0[3], part, pr[3]);
    }
    // reduce the 9 partials across the 16-lane la-group (xor masks stay in-group)
    #pragma unroll
    for (int m = 1; m < 16; m <<= 1) {
        #pragma unroll
        for (int q = 0; q < 4; ++q) {
            sq[q] += __shfl_xor(sq[q], m, 64);
            pr[q] += __shfl_xor(pr[q], m, 64);
        }
        sq16 += __shfl_xor(sq16, m, 64);
    }
    // n1[r+1] for q==3 (row lg*4+4): next lg's sq[0]; lg==3 -> n1[16]=sq16
    float sqn3 = __shfl(sq[0], (lane + 16) & 63);
    if (lg == 3) sqn3 = sq16;

    // ---- P3: scores for rows r = lg*4+q (stay in the producing lane) ----
    const float gate0 = gate[0];
    float flo_[4], frac_[4];
    #pragma unroll
    for (int q = 0; q < 4; ++q) {
        int l = l0 + lg * 4 + q;
        float n1a = sq[q];
        float n1b = (q < 3) ? sq[q + 1] : sqn3;
        float gg  = pr[q];
        float d1a = sqrtf(n1a), d1b = sqrtf(n1b);
        float dd  = sqrtf(fmaxf(n1a + n1b + 2.f * gg, 0.f));  // ||D_r + D_{r+1}||
        float sc  = fmaxf(1.f - ((d1a + d1b) - dd) / fmaxf(dd, 1e-6f), 0.f);
        float bet = (l >= 1 && l <= L_SEQ - 2) ? sc * (1.f / (L_SEQ - 2)) : 0.f;
        float adjust = gate0 * (bet - 0.5f) * 0.1f;
        float ap  = fminf(fmaxf((float)l + adjust, 0.f), (float)(L_SEQ - 1));
        flo_[q]  = floorf(ap);
        frac_[q] = ap - flo_[q];
    }

    // ---- P4: RoPE epilogue — lane (la,lg) writes rows lg*4+it, pairs 2la,2la+1 ----
    {
        // fj/(2pi) for j=2la and j=2la+1, computed DIRECTLY (R6 bug: the
        // ratio constant 10000^(-1/32)=0.7498942 was mistyped as 0.79536)
        const float fja = __builtin_exp2f(-0.4152410118609203f * (float)(2 * la))
                        * 0.15915494309189535f;
        const float fjb = __builtin_exp2f(-0.4152410118609203f * (float)(2 * la + 1))
                        * 0.15915494309189535f;
        const float cfa = __builtin_amdgcn_cosf(fja), sfa = __builtin_amdgcn_sinf(fja);
        const float cfb = __builtin_amdgcn_cosf(fjb), sfb = __builtin_amdgcn_sinf(fjb);
        const float cfma = cfa - 1.0f, cfmb = cfb - 1.0f;
        #pragma unroll
        for (int it = 0; it < 4; ++it) {
            int l = l0 + lg * 4 + it;
            float flo = flo_[it], fr = frac_[it];
            const float* xp = x + bh_off + l * (HEADS * DIM) + 4 * la;
            float4 xv = *(const float4*)xp;
            // pair a (j=2la)
            float ta  = flo * fja;
            float rva = ta - floorf(ta);
            float cla = __builtin_amdgcn_cosf(rva), sla = __builtin_amdgcn_sinf(rva);
            float ua  = fmaf(fr, cfma, 1.0f);
            float va  = fr * sfa;
            float cia = fmaf(-sla, va, cla * ua);
            float sia = fmaf(cla, va, sla * ua);
            // pair b (j=2la+1)
            float tb  = flo * fjb;
            float rvb = tb - floorf(tb);
            float clb = __builtin_amdgcn_cosf(rvb), slb = __builtin_amdgcn_sinf(rvb);
            float ub  = fmaf(fr, cfmb, 1.0f);
            float vb  = fr * sfb;
            float cib = fmaf(-slb, vb, clb * ub);
            float sib = fmaf(clb, vb, slb * ub);
            float4 o;
            o.x = xv.x * cia - xv.y * sia;
            o.y = fmaf(xv.y, cia, xv.x * sia);
            o.z = xv.z * cib - xv.w * sib;
            o.w = fmaf(xv.w, cib, xv.z * sib);
            *(float4*)(out + bh_off + l * (HEADS * DIM) + 4 * la) = o;
        }
    }
}

extern "C" void kernel_launch(void* const* d_in, const int* in_sizes, int n_in,
                              void* d_out, int out_size, void* d_ws, size_t ws_size,
                              hipStream_t stream) {
    const float* x    = (const float*)d_in[0];
    const float* W    = (const float*)d_in[1];
    const float* gate = (const float*)d_in[3];   // bias cancels in differences
    float* out = (float*)d_out;

    const int B = in_sizes[0] / (L_SEQ * HEADS * DIM);

    unsigned short* wbf = nullptr;
    if (ws_size >= (size_t)(DIM * DIM * sizeof(unsigned short))) {
        wbf = (unsigned short*)d_ws;
        prep_w_kernel<<<16, 256, 0, stream>>>(W, wbf);
    }

    dim3 grid(L_SEQ / (TILE * 4), HEADS, B);
    betweenness_rope_kernel<<<grid, 256, 0, stream>>>(x, W, wbf, gate, out);
}